// Round 9
// baseline (127.255 us; speedup 1.0000x reference)
//
#include <hip/hip_runtime.h>
#include <cstdint>

#define IN_F   4096
#define OUT_F  14336
#define GROUP  128
#define KROT   8
#define BATCH  16
#define NJP    1792           // packed words per weight row
#define NG     32             // quant groups

typedef __attribute__((ext_vector_type(8))) short short8;  // 8 bf16
typedef __attribute__((ext_vector_type(4))) float f32x4;

// Module-scope scratch (no d_ws dependence).
__device__ uint32_t g_xa[BATCH * IN_F / 2];    // rotated activations, bf16 pairs
__device__ float    g_rs[NG * BATCH];          // per-(group,row) sums of bf16 acts

static __device__ __forceinline__ unsigned short f2bf(float f) {
    union { float f; uint32_t i; } v; v.f = f;
    uint32_t u = v.i;
    uint32_t r = u + 0x7FFFu + ((u >> 16) & 1u);  // RNE
    return (unsigned short)(r >> 16);
}
static __device__ __forceinline__ float bf2f(uint32_t u16) {
    union { uint32_t i; float f; } v; v.i = u16 << 16; return v.f;
}

// ---------------------------------------------------------------------------
// Kernel 1: rotation layers + bf16 pack + per-group row-sums of the rounded
// bf16 activations (for the zero-point correction identity). Unchanged from
// round 8 (verified: absmax 0.0625).
// ---------------------------------------------------------------------------
__global__ __launch_bounds__(1024) void k_rotate(
    const float* __restrict__ x,      // [16][4096] f32 (fp16 promoted)
    const float* __restrict__ theta,  // [8][2048]  f32
    const int*   __restrict__ pairs,  // [8][4096]  int32
    const float* __restrict__ cscale) // [4096]     f32
{
    __shared__ float row[IN_F];
    const int b   = blockIdx.x;
    const int tid = threadIdx.x;

    int2  ij0[KROT], ij1[KROT];
    float c0[KROT], s0[KROT], c1[KROT], s1[KROT];
#pragma unroll
    for (int k = 0; k < KROT; ++k) {
        const int2*  pk = (const int2*)(pairs + k * IN_F);
        const float* tk = theta + k * (IN_F / 2);
        ij0[k] = pk[tid];
        ij1[k] = pk[tid + 1024];
        __sincosf(tk[tid],        &s0[k], &c0[k]);
        __sincosf(tk[tid + 1024], &s1[k], &c1[k]);
    }

    for (int i = tid; i < IN_F; i += 1024) row[i] = x[b * IN_F + i];
    __syncthreads();

#pragma unroll
    for (int k = 0; k < KROT; ++k) {
        float a0 = row[ij0[k].x], b0 = row[ij0[k].y];
        float a1 = row[ij1[k].x], b1 = row[ij1[k].y];
        row[ij0[k].x] = c0[k] * a0 - s0[k] * b0;
        row[ij0[k].y] = s0[k] * a0 + c0[k] * b0;
        row[ij1[k].x] = c1[k] * a1 - s1[k] * b1;
        row[ij1[k].y] = s1[k] * a1 + c1[k] * b1;
        __syncthreads();
    }

    float p0, p1;
    {
        int i = tid;
        uint32_t lo = f2bf(row[2 * i]     * cscale[2 * i]);
        uint32_t hi = f2bf(row[2 * i + 1] * cscale[2 * i + 1]);
        g_xa[b * (IN_F / 2) + i] = lo | (hi << 16);
        p0 = bf2f(lo) + bf2f(hi);
        i = tid + 1024;
        lo = f2bf(row[2 * i]     * cscale[2 * i]);
        hi = f2bf(row[2 * i + 1] * cscale[2 * i + 1]);
        g_xa[b * (IN_F / 2) + i] = lo | (hi << 16);
        p1 = bf2f(lo) + bf2f(hi);
    }
#pragma unroll
    for (int m = 1; m < 64; m <<= 1) {
        p0 += __shfl_xor(p0, m, 64);
        p1 += __shfl_xor(p1, m, 64);
    }
    if ((tid & 63) == 0) {
        const int w = tid >> 6;
        g_rs[w * BATCH + b]        = p0;
        g_rs[(16 + w) * BATCH + b] = p1;
    }
}

// ---------------------------------------------------------------------------
// Kernel 2: MFMA dequant-GEMM, BARRIER-FREE main loop. Block = 32 out-cols;
// the 4 waves split K (wave w -> groups 8w..8w+7), each staging dequantized
// bf16(128+v) into its PRIVATE LDS region (32 cols x 16 k-octet cells x 17
// pitch). ds_write -> ds_read -> MFMA is wave-synchronous via lgkmcnt; no
// __syncthreads until the single cross-wave reduction at the end (R8 had 16
// barriers/block at 2 waves/SIMD = the m97 barrier-drain disease).
// d_out written directly -> k_reduce + g_part eliminated.
// ---------------------------------------------------------------------------
__global__ __launch_bounds__(256) void k_gemm(
    const int*   __restrict__ qweight, // [4096][1792] int32
    const int*   __restrict__ qzeros,  // [32][1792]   int32
    const float* __restrict__ scales,  // [32][14336]  f32
    float*       __restrict__ out)     // [16][14336]  f32 = d_out
{
    __shared__ uint4 ldsb[4 * 32 * 17];   // 4 wave-private regions, 34816 B

    const int tid  = threadIdx.x;
    const int bn   = blockIdx.x;          // 0..447
    const int n0   = bn * 32;
    const int jp0  = bn * 4;              // 4 packed words per block
    const int w    = tid >> 6;            // wave 0..3 = K-chunk
    const int lane = tid & 63;
    const int jps  = lane & 3;            // staging word 0..3
    const int koct = lane >> 2;           // staging k-octet 0..15
    const int mrow = lane & 15;           // MFMA row / col lane
    const int quad = lane >> 4;
    const int nl0  = mrow;                // tile-0 local col
    const int nl1  = mrow + 16;           // tile-1 local col
    const int sw0  = mrow >> 3;           // read swizzle keys
    const int sw1  = 2 + (mrow >> 3);
    const int xsw  = koct ^ jps;          // write swizzle slot

    uint4* ldsw = ldsb + w * (32 * 17);

    // ---- prologue: hoist scales, zero-points, row-sums for this wave's 8
    //      groups into registers --------------------------------------------
    float s0v[8], s1v[8], t0v[8], t1v[8];
    f32x4 rsv[8];
    {
        const int jz0 = jp0 + (nl0 >> 3);
        const int jz1 = jp0 + (nl1 >> 3);
        const int sh  = 4 * (mrow & 7);
#pragma unroll
        for (int g = 0; g < 8; ++g) {
            const int gg = w * 8 + g;
            s0v[g] = scales[(size_t)gg * OUT_F + n0 + nl0];
            s1v[g] = scales[(size_t)gg * OUT_F + n0 + nl1];
            const float z0 = 128.0f + (float)(((uint32_t)qzeros[gg * NJP + jz0] >> sh) & 15u);
            const float z1 = 128.0f + (float)(((uint32_t)qzeros[gg * NJP + jz1] >> sh) & 15u);
            t0v[g] = s0v[g] * z0;
            t1v[g] = s1v[g] * z1;
            rsv[g] = *(const f32x4*)(g_rs + gg * BATCH + quad * 4);
        }
    }

    f32x4 m0 = {0.f, 0.f, 0.f, 0.f};
    f32x4 m1 = {0.f, 0.f, 0.f, 0.f};

    for (int st = 0; st < 8; ++st) {
        const int g   = w * 8 + st;
        const int kr0 = g * GROUP + koct * 8;

        uint32_t wc[8];
#pragma unroll
        for (int i = 0; i < 8; ++i)
            wc[i] = (uint32_t)qweight[(size_t)(kr0 + i) * NJP + jp0 + jps];

        uint4 ac[4];
        const uint32_t* apst = g_xa + mrow * (IN_F / 2) + w * 512 + st * 64 + quad * 4;
#pragma unroll
        for (int kt = 0; kt < 4; ++kt) ac[kt] = *(const uint4*)(apst + kt * 16);

        // dequant: bf16(128+v) by bit-OR; col n_loc = jps*8+c, k-octet koct
#pragma unroll
        for (int c = 0; c < 8; ++c) {
            uint4 cell;
            uint32_t pk[4];
#pragma unroll
            for (int h = 0; h < 4; ++h) {
                uint32_t lo = (wc[2 * h]     >> (4 * c)) & 15u;
                uint32_t hi = (wc[2 * h + 1] >> (4 * c)) & 15u;
                pk[h] = 0x43004300u | lo | (hi << 16);
            }
            cell.x = pk[0]; cell.y = pk[1]; cell.z = pk[2]; cell.w = pk[3];
            ldsw[(jps * 8 + c) * 17 + xsw] = cell;
        }

        // wave-synchronous: lgkmcnt ordering only, no barrier
        f32x4 ga = {0.f, 0.f, 0.f, 0.f};
        f32x4 gb = {0.f, 0.f, 0.f, 0.f};
#pragma unroll
        for (int kt = 0; kt < 4; ++kt) {
            union { uint4 q; short8 s; } af, b0, b1;
            af.q = ac[kt];
            const int ko = kt * 4 + quad;
            b0.q = ldsw[nl0 * 17 + (ko ^ sw0)];
            b1.q = ldsw[nl1 * 17 + (ko ^ sw1)];
            ga = __builtin_amdgcn_mfma_f32_16x16x32_bf16(af.s, b0.s, ga, 0, 0, 0);
            gb = __builtin_amdgcn_mfma_f32_16x16x32_bf16(af.s, b1.s, gb, 0, 0, 0);
        }

        // per-group fold: m += s*ga - (s*(128+iz))*rowsum
#pragma unroll
        for (int r = 0; r < 4; ++r) {
            m0[r] = fmaf(s0v[st], ga[r], fmaf(-t0v[st], rsv[st][r], m0[r]));
            m1[r] = fmaf(s1v[st], gb[r], fmaf(-t1v[st], rsv[st][r], m1[r]));
        }
    }

    // ---- epilogue: cross-wave K-reduction in LDS, direct store ------------
    // wave-private partials -> own staging region (reused; done with it)
    float* redw = (float*)(ldsb + w * (32 * 17));
#pragma unroll
    for (int r = 0; r < 4; ++r) {
        redw[(quad * 4 + r) * 16 + mrow]       = m0[r];
        redw[256 + (quad * 4 + r) * 16 + mrow] = m1[r];
    }
    __syncthreads();

    const float* redf = (const float*)ldsb;
    const int col  = tid & 31;            // 0..31
    const int tile = col >> 4;
    const int c16  = col & 15;
    const int r0   = tid >> 5;            // 0..7 (rows r0 and r0+8)
    float sA = 0.f, sB = 0.f;
#pragma unroll
    for (int ww = 0; ww < 4; ++ww) {
        const float* base = redf + ww * (32 * 17 * 4) + tile * 256 + c16;
        sA += base[r0 * 16];
        sB += base[(r0 + 8) * 16];
    }
    out[(size_t)r0 * OUT_F + n0 + col]       = sA;
    out[(size_t)(r0 + 8) * OUT_F + n0 + col] = sB;
}

extern "C" void kernel_launch(void* const* d_in, const int* in_sizes, int n_in,
                              void* d_out, int out_size, void* d_ws, size_t ws_size,
                              hipStream_t stream) {
    const float* x       = (const float*)d_in[0];
    const float* theta   = (const float*)d_in[1];
    const int*   pairs   = (const int*)d_in[2];
    const float* cscale  = (const float*)d_in[3];
    const int*   qweight = (const int*)d_in[4];
    const int*   qzeros  = (const int*)d_in[5];
    const float* scales  = (const float*)d_in[6];
    float*       out     = (float*)d_out;
    (void)d_ws; (void)ws_size;

    k_rotate<<<16, 1024, 0, stream>>>(x, theta, pairs, cscale);
    k_gemm<<<448, 256, 0, stream>>>(qweight, qzeros, scales, out);
}

// Round 10
// 102.607 us; speedup vs baseline: 1.2402x; 1.2402x over previous
//
#include <hip/hip_runtime.h>
#include <cstdint>

#define IN_F   4096
#define OUT_F  14336
#define GROUP  128
#define KROT   8
#define BATCH  16
#define NJP    1792           // packed words per weight row
#define NG     32             // quant groups

typedef __attribute__((ext_vector_type(8))) short short8;  // 8 bf16
typedef __attribute__((ext_vector_type(4))) float f32x4;

// Module-scope scratch (no d_ws dependence).
__device__ uint32_t g_xa[BATCH * IN_F / 2];    // rotated activations, bf16 pairs
__device__ float    g_rs[NG * BATCH];          // per-(group,row) sums of bf16 acts
__device__ float    g_part[4 * BATCH * OUT_F]; // 4 K-chunk fp32 partials

static __device__ __forceinline__ unsigned short f2bf(float f) {
    union { float f; uint32_t i; } v; v.f = f;
    uint32_t u = v.i;
    uint32_t r = u + 0x7FFFu + ((u >> 16) & 1u);  // RNE
    return (unsigned short)(r >> 16);
}
static __device__ __forceinline__ float bf2f(uint32_t u16) {
    union { uint32_t i; float f; } v; v.i = u16 << 16; return v.f;
}

// ---------------------------------------------------------------------------
// Kernel 1: rotation layers + bf16 pack + per-group row-sums (verified R8).
// ---------------------------------------------------------------------------
__global__ __launch_bounds__(1024) void k_rotate(
    const float* __restrict__ x,      // [16][4096] f32 (fp16 promoted)
    const float* __restrict__ theta,  // [8][2048]  f32
    const int*   __restrict__ pairs,  // [8][4096]  int32
    const float* __restrict__ cscale) // [4096]     f32
{
    __shared__ float row[IN_F];
    const int b   = blockIdx.x;
    const int tid = threadIdx.x;

    int2  ij0[KROT], ij1[KROT];
    float c0[KROT], s0[KROT], c1[KROT], s1[KROT];
#pragma unroll
    for (int k = 0; k < KROT; ++k) {
        const int2*  pk = (const int2*)(pairs + k * IN_F);
        const float* tk = theta + k * (IN_F / 2);
        ij0[k] = pk[tid];
        ij1[k] = pk[tid + 1024];
        __sincosf(tk[tid],        &s0[k], &c0[k]);
        __sincosf(tk[tid + 1024], &s1[k], &c1[k]);
    }

    for (int i = tid; i < IN_F; i += 1024) row[i] = x[b * IN_F + i];
    __syncthreads();

#pragma unroll
    for (int k = 0; k < KROT; ++k) {
        float a0 = row[ij0[k].x], b0 = row[ij0[k].y];
        float a1 = row[ij1[k].x], b1 = row[ij1[k].y];
        row[ij0[k].x] = c0[k] * a0 - s0[k] * b0;
        row[ij0[k].y] = s0[k] * a0 + c0[k] * b0;
        row[ij1[k].x] = c1[k] * a1 - s1[k] * b1;
        row[ij1[k].y] = s1[k] * a1 + c1[k] * b1;
        __syncthreads();
    }

    float p0, p1;
    {
        int i = tid;
        uint32_t lo = f2bf(row[2 * i]     * cscale[2 * i]);
        uint32_t hi = f2bf(row[2 * i + 1] * cscale[2 * i + 1]);
        g_xa[b * (IN_F / 2) + i] = lo | (hi << 16);
        p0 = bf2f(lo) + bf2f(hi);
        i = tid + 1024;
        lo = f2bf(row[2 * i]     * cscale[2 * i]);
        hi = f2bf(row[2 * i + 1] * cscale[2 * i + 1]);
        g_xa[b * (IN_F / 2) + i] = lo | (hi << 16);
        p1 = bf2f(lo) + bf2f(hi);
    }
#pragma unroll
    for (int m = 1; m < 64; m <<= 1) {
        p0 += __shfl_xor(p0, m, 64);
        p1 += __shfl_xor(p1, m, 64);
    }
    if ((tid & 63) == 0) {
        const int w = tid >> 6;
        g_rs[w * BATCH + b]        = p0;
        g_rs[(16 + w) * BATCH + b] = p1;
    }
}

// ---------------------------------------------------------------------------
// Kernel 2: MFMA dequant-GEMM: coalesced fetch (R8 geometry: 128-col blocks,
// 64B per qweight row -> R9's 4x over-fetch fixed) AND barrier-free main loop
// (R9 idea: waves privately own 256 k = 2 groups; wave-synchronous LDS).
// Per 32k sub-chunk: stage [k-octet][col] cells in the wave's 8KB region;
// write cols permuted by cc^(jp&7) -> 8 accesses/bank (conflict-free); reads
// are naturally uniform. One A-frag load feeds 8 MFMAs (n-tiles).
// ---------------------------------------------------------------------------
__global__ __launch_bounds__(256, 2) void k_gemm(
    const int*   __restrict__ qweight, // [4096][1792] int32
    const int*   __restrict__ qzeros,  // [32][1792]   int32
    const float* __restrict__ scales)  // [32][14336]  f32
{
    __shared__ uint4 ldsb[4 * 512];    // 4 wave-private 8KB regions (32 KB)

    const int tid  = threadIdx.x;
    const int bn   = blockIdx.x % 112;
    const int bk   = blockIdx.x / 112;    // K-chunk 0..3
    const int n0   = bn * 128;
    const int jp0  = bn * 16;             // 16 packed words per block row
    const int w    = tid >> 6;            // wave 0..3: k-range w*256 within chunk
    const int lane = tid & 63;
    const int jp   = lane & 15;           // staging word 0..15
    const int rr   = lane >> 4;           // staging k-octet 0..3
    const int mrow = lane & 15;           // MFMA m-row / n-col lane
    const int quad = lane >> 4;

    uint4* ldsw = ldsb + w * 512;

    // ---- prologue: hoist per-(group, n-tile) scales / zero-terms / rowsums
    float sv[2][8], tv[2][8];
    f32x4 rsv[2];
    {
        const int sh = 4 * (mrow & 7);
#pragma unroll
        for (int gi = 0; gi < 2; ++gi) {
            const int gg = bk * 8 + w * 2 + gi;
            rsv[gi] = *(const f32x4*)(g_rs + gg * BATCH + quad * 4);
#pragma unroll
            for (int t = 0; t < 8; ++t) {
                const int col = n0 + t * 16 + mrow;
                const float s = scales[(size_t)gg * OUT_F + col];
                const float z = 128.0f +
                    (float)(((uint32_t)qzeros[gg * NJP + (col >> 3)] >> sh) & 15u);
                sv[gi][t] = s;
                tv[gi][t] = s * z;
            }
        }
    }

    f32x4 m[8];
#pragma unroll
    for (int t = 0; t < 8; ++t) m[t] = (f32x4){0.f, 0.f, 0.f, 0.f};

#pragma unroll
    for (int gi = 0; gi < 2; ++gi) {
        const int gg = bk * 8 + w * 2 + gi;

        f32x4 ga[8];
#pragma unroll
        for (int t = 0; t < 8; ++t) ga[t] = (f32x4){0.f, 0.f, 0.f, 0.f};

#pragma unroll
        for (int sc = 0; sc < 4; ++sc) {
            const int kr0 = gg * GROUP + sc * 32 + rr * 8;

            uint32_t wc[8];
#pragma unroll
            for (int i = 0; i < 8; ++i)
                wc[i] = (uint32_t)qweight[(size_t)(kr0 + i) * NJP + jp0 + jp];

            // A-frag for this 32-k tile (reused by all 8 n-tiles)
            union { uint4 q; short8 s; } af;
            af.q = *(const uint4*)(g_xa + mrow * (IN_F / 2)
                                   + ((gg * GROUP + sc * 32) >> 1) + quad * 4);

            // dequant: bf16(128+v) bit-OR; col permuted so each ds_write
            // covers all 32 banks (col&7 = cc^(jp&7) spans 0..7 across wave)
#pragma unroll
            for (int cc = 0; cc < 8; ++cc) {
                const int c  = cc ^ (jp & 7);
                const int sh = 4 * c;
                uint4 cell;
                uint32_t pk[4];
#pragma unroll
                for (int h = 0; h < 4; ++h) {
                    uint32_t lo = (wc[2 * h]     >> sh) & 15u;
                    uint32_t hi = (wc[2 * h + 1] >> sh) & 15u;
                    pk[h] = 0x43004300u | lo | (hi << 16);
                }
                cell.x = pk[0]; cell.y = pk[1]; cell.z = pk[2]; cell.w = pk[3];
                ldsw[rr * 128 + jp * 8 + c] = cell;   // [k-octet][col]
            }

            // wave-synchronous (lgkmcnt only): 8 n-tiles x 1 k-tile
#pragma unroll
            for (int t = 0; t < 8; ++t) {
                union { uint4 q; short8 s; } bf;
                bf.q = ldsw[quad * 128 + t * 16 + mrow];
                ga[t] = __builtin_amdgcn_mfma_f32_16x16x32_bf16(af.s, bf.s, ga[t], 0, 0, 0);
            }
        }

        // per-group fold: m += s*ga - (s*(128+iz))*rowsum
#pragma unroll
        for (int t = 0; t < 8; ++t)
#pragma unroll
            for (int r = 0; r < 4; ++r)
                m[t][r] = fmaf(sv[gi][t], ga[t][r],
                               fmaf(-tv[gi][t], rsv[gi][r], m[t][r]));
    }

    // ---- epilogue: wave partials -> own LDS region; one barrier; 4-way sum
    float* fw = (float*)ldsb + w * 2048;   // [row 16][col 128]
#pragma unroll
    for (int t = 0; t < 8; ++t)
#pragma unroll
        for (int r = 0; r < 4; ++r)
            fw[(quad * 4 + r) * 128 + t * 16 + mrow] = m[t][r];
    __syncthreads();

    const float* fb   = (const float*)ldsb;
    const int    colg = (tid & 31) * 4;    // 0..124
    const int    row  = tid >> 5;          // 0..7 (handles row and row+8)
    f32x4 sA = {0.f, 0.f, 0.f, 0.f}, sB = {0.f, 0.f, 0.f, 0.f};
#pragma unroll
    for (int ww = 0; ww < 4; ++ww) {
        sA += *(const f32x4*)(fb + ww * 2048 + row * 128 + colg);
        sB += *(const f32x4*)(fb + ww * 2048 + (row + 8) * 128 + colg);
    }
    float* pp = g_part + (size_t)bk * BATCH * OUT_F + n0 + colg;
    *(f32x4*)(pp + (size_t)row * OUT_F)       = sA;
    *(f32x4*)(pp + (size_t)(row + 8) * OUT_F) = sB;
}

// ---------------------------------------------------------------------------
// Kernel 3: sum the 4 K-chunk partials -> d_out. float4 per thread.
// ---------------------------------------------------------------------------
__global__ __launch_bounds__(128) void k_reduce(float* __restrict__ out)
{
    const int t = blockIdx.x * 128 + threadIdx.x;   // 0..57343
    const size_t j = (size_t)t * 4;
    float4 a = *(const float4*)(g_part + j);
    float4 b = *(const float4*)(g_part + (size_t)BATCH * OUT_F + j);
    float4 c = *(const float4*)(g_part + (size_t)2 * BATCH * OUT_F + j);
    float4 d = *(const float4*)(g_part + (size_t)3 * BATCH * OUT_F + j);
    float4 s;
    s.x = (a.x + b.x) + (c.x + d.x);
    s.y = (a.y + b.y) + (c.y + d.y);
    s.z = (a.z + b.z) + (c.z + d.z);
    s.w = (a.w + b.w) + (c.w + d.w);
    *(float4*)(out + j) = s;
}

extern "C" void kernel_launch(void* const* d_in, const int* in_sizes, int n_in,
                              void* d_out, int out_size, void* d_ws, size_t ws_size,
                              hipStream_t stream) {
    const float* x       = (const float*)d_in[0];
    const float* theta   = (const float*)d_in[1];
    const int*   pairs   = (const int*)d_in[2];
    const float* cscale  = (const float*)d_in[3];
    const int*   qweight = (const int*)d_in[4];
    const int*   qzeros  = (const int*)d_in[5];
    const float* scales  = (const float*)d_in[6];
    float*       out     = (float*)d_out;
    (void)d_ws; (void)ws_size;

    k_rotate<<<16, 1024, 0, stream>>>(x, theta, pairs, cscale);
    k_gemm<<<448, 256, 0, stream>>>(qweight, qzeros, scales);
    k_reduce<<<(BATCH * OUT_F) / (128 * 4), 128, 0, stream>>>(out);
}